// Round 20
// baseline (195.940 us; speedup 1.0000x reference)
//
#include <hip/hip_runtime.h>
#include <math.h>

// RecurNN: B=256, L=256, E=100, T=255.
// x_t = W1L*left_t + W1R*right_t + b1; h_t = tanh(x_t); out = sigmoid(W2 h_254 + b2).
// These inputs: right_t always a leaf; left_t = node t-1 (leaf only at t=0).
//
// R20 = R19 (131us) with the PRODUCER rebuilt around v_pk_fma_f32:
//  - emb quarter staged in LDS (lane-stride-1 write at tick i of the row for
//    t=i+4, loaded at tick i-1; 3-tick global flight), consumed at tick t-2 as
//    13 uniform ds_read_b64 -> natural float2 (h_k,h_k+1) pairs.
//  - 26 v_pk_fma_f32 (rows lc, lc+50 x 13 k-pairs, all-VGPR operands, default
//    op_sel) replace 25 RL + 50 fma: producer VALU ~110 -> ~47 instr/tick.
//  - tok<0 (right-internal, never these inputs) stages ZEROS -> cpart = b1;
//    consumer slow_dot supplies the W1R*hist term (unchanged generality).
// Consumer unchanged (RL from own vh = the no-second-barrier trick; R19 layout,
// setprio, hoisted cpart read). One "lgkmcnt(0); s_barrier" per tick.

#define Bc 256
#define Lc 256
#define Ec 100
#define Tc 255
#define W1cols 200

#define RL(v, k) __int_as_float(__builtin_amdgcn_readlane(__float_as_int(v), (k)))
#define RF(x)    __builtin_amdgcn_readfirstlane(x)

// ---- consumer: 25 weight pairs (50 named scalars) ----
#define REP25(X) X(0) X(1) X(2) X(3) X(4) X(5) X(6) X(7) X(8) X(9) X(10) X(11) X(12) \
                 X(13) X(14) X(15) X(16) X(17) X(18) X(19) X(20) X(21) X(22) X(23) X(24)
#define DECLWC(j) float wA##j, wB##j;
#define LOADWC(j) { wA##j = crowA[j]; wB##j = crowB[j]; }
#define CM2(a,b) { const float ra_ = RL(sv,(a)), rb_ = RL(sv,(b)); \
    accA0 = fmaf(ra_, wA##a, accA0); accB0 = fmaf(ra_, wB##a, accB0); \
    accA1 = fmaf(rb_, wA##b, accA1); accB1 = fmaf(rb_, wB##b, accB1); }
#define CM1(a) { const float ra_ = RL(sv,(a)); \
    accA0 = fmaf(ra_, wA##a, accA0); accB0 = fmaf(ra_, wB##a, accB0); }
#define CMALL CM2(0,1) CM2(2,3) CM2(4,5) CM2(6,7) CM2(8,9) CM2(10,11) CM2(12,13) \
              CM2(14,15) CM2(16,17) CM2(18,19) CM2(20,21) CM2(22,23) CM1(24)

// ---- producer: 13 float2 weight pairs per row (k-pairs), pk_fma ----
#define REP13(X) X(0) X(1) X(2) X(3) X(4) X(5) X(6) X(7) X(8) X(9) X(10) X(11) X(12)
#define DECLWP(j) float2 pA##j, pB##j;
#define LOADWP(j) { pA##j = make_float2(prowA[2*(j)], (2*(j)+1 < 25) ? prowA[2*(j)+1] : 0.f); \
                    pB##j = make_float2(prowB[2*(j)], (2*(j)+1 < 25) ? prowB[2*(j)+1] : 0.f); }
// packed fma: A.{x,y} += W.{x,y} * H.{x,y}   (all 64-bit VGPR pairs)
#define PPK(A, W, H) asm volatile("v_pk_fma_f32 %0, %1, %2, %0" : "+v"(A) : "v"(W), "v"(H));
#define PSTEP(j) { const float2 h_ = *(const float2*)(eb + 2*(j)); \
                   PPK(aA, pA##j, h_) PPK(aB, pB##j, h_) }
#define PCOMP(T) { \
    const float* eb = &embS[(T) & 3][q][0]; \
    float2 aA = make_float2(b1eA, 0.f), aB = make_float2(b1eB, 0.f); \
    REP13(PSTEP) \
    if (l < 50) { \
        cpart[(T) & 7][q][lc]      = aA.x + aA.y; \
        cpart[(T) & 7][q][lc + 50] = aB.x + aB.y; \
    } }

// generic fallback dot (global weights; never hot for these inputs)
__device__ __noinline__ float slow_dot(const float* rp, const float* wr) {
    float a0 = 0.f, a1 = 0.f, a2 = 0.f, a3 = 0.f;
    for (int qq = 0; qq < 25; ++qq) {
        float4 h4 = *(const float4*)(rp + 4 * qq);
        float4 w4 = *(const float4*)(wr + 4 * qq);
        a0 = fmaf(w4.x, h4.x, a0); a1 = fmaf(w4.y, h4.y, a1);
        a2 = fmaf(w4.z, h4.z, a2); a3 = fmaf(w4.w, h4.w, a3);
    }
    return (a0 + a1) + (a2 + a3);
}

__global__ __launch_bounds__(512, 2)
void fused(const int* __restrict__ token_ids,
           const int* __restrict__ comp_left,
           const int* __restrict__ comp_right,
           const float* __restrict__ emb,
           const float* __restrict__ W1,
           const float* __restrict__ b1,
           const float* __restrict__ W2,
           const float* __restrict__ b2,
           float* __restrict__ out)
{
    const int b    = blockIdx.x;
    const int tid  = threadIdx.x;          // 0..511
    const int wv   = tid >> 6;             // 0..3 consumers; 4..7 producers
    const int l    = tid & 63;
    const bool cons = (wv < 4);
    const int q    = wv & 3;               // consumer k-slice / producer k-quarter
    const int lc   = (l < 50) ? l : 49;

    __shared__ float hist[Tc * Ec];                  // generic paths only
    __shared__ float part[2][4][Ec];                 // cons partials, stride-1
    __shared__ float cpart[8][4][Ec];                // c partials, stride-1
    __shared__ __align__(16) float embS[4][4][28];   // emb quarter ring (padded)
    __shared__ int2  ccS[Tc];
    __shared__ int   tokRS[Tc], tokLS[Tc];
    __shared__ float red[4];

    // ---- staging ----
    for (int i = tid; i < Tc; i += 512) {
        const int cl = comp_left [b * Tc + i];
        const int cr = comp_right[b * Tc + i];
        ccS[i]   = make_int2(cl, cr);
        tokRS[i] = (cr < Lc) ? token_ids[b * Lc + cr] : -1;
        tokLS[i] = (cl < Lc) ? token_ids[b * Lc + cl] : -1;
    }

    // ---- weights ----
    // consumer: W1L rows (lc, lc+50), k-slice [25q, 25q+25) as scalars
    const float* crowA = W1 + (size_t)lc * W1cols + 25 * q;
    const float* crowB = W1 + (size_t)(lc + 50) * W1cols + 25 * q;
    REP25(DECLWC)
    // producer: W1R rows (lc, lc+50), k-quarter as float2 k-pairs
    const float* prowA = W1 + (size_t)lc * W1cols + Ec + 25 * q;
    const float* prowB = W1 + (size_t)(lc + 50) * W1cols + Ec + 25 * q;
    REP13(DECLWP)
    if (cons) { REP25(LOADWC) }
    else      { REP13(LOADWP) }
    // producer wave q==0 carries b1
    const float b1eA = (!cons && q == 0) ? b1[lc] : 0.f;
    const float b1eB = (!cons && q == 0) ? b1[lc + 50] : 0.f;

    __syncthreads();   // staging + weights visible

    // ---- state ----
    float vh = 0.f;                        // consumer lane j<25: h[25q+j]
    int2  cc = make_int2(0, 0);
    float eR = 0.f;                        // producer in-flight emb element

    if (cons) {
        cc = ccS[0];
    } else {
        // ---- producer prologue: stage slots t=0..3; cpart[0],[1]; load t=4 ----
        #pragma unroll
        for (int t = 0; t < 4; ++t) {
            const int tk = RF(tokRS[t]);
            float v = 0.f;
            if (tk >= 0 && l < 25) v = emb[(size_t)tk * Ec + 25 * q + l];
            if (l < 25) embS[t][q][l] = v;
        }
        PCOMP(0)      // own-wave write->read: DS pipe in-order, no barrier needed
        PCOMP(1)
        const int tk4 = RF(tokRS[4]);
        if (tk4 >= 0 && l < 25) eR = emb[(size_t)tk4 * Ec + 25 * q + l];
    }

#define BARRIER asm volatile("s_waitcnt lgkmcnt(0)\n\ts_barrier" ::: "memory");

// one tick: I runtime index, PPc compile-time cons ping-pong
#define TICK(I, PPc)                                                          \
{                                                                             \
    const int i_ = (I);                                                       \
    if (cons) {                                                               \
        const int tc = i_ - 1;                                                \
        if (tc >= 0) {                                                        \
            __builtin_amdgcn_s_setprio(1);                                    \
            const int li = RF(cc.x);                                          \
            const int ri = RF(cc.y);                                          \
            /* cpart[tc] written at tick tc-2 (>=2 barriers ago): read early  \
               so its LDS latency hides under CMALL issue. */                 \
            float cp0 = 0.f, cp1 = 0.f, cp2 = 0.f, cp3 = 0.f;                 \
            if (l < 25) {                                                     \
                const int r_ = 25 * q + l;                                    \
                cp0 = cpart[tc & 7][0][r_]; cp1 = cpart[tc & 7][1][r_];       \
                cp2 = cpart[tc & 7][2][r_]; cp3 = cpart[tc & 7][3][r_];       \
            }                                                                 \
            float sv = 0.f;                                                   \
            if (tc >= 1 && li == Lc + tc - 1) {                               \
                sv = vh;                       /* register fast path */       \
            } else if (li >= Lc) {                                            \
                const int n = li - Lc;                                        \
                if (n < tc && l < 25) sv = hist[n * Ec + 25 * q + l];         \
            } else {                                                          \
                const int tl = RF(tokLS[tc]);                                 \
                if (tl >= 0 && l < 25) sv = emb[(size_t)tl * Ec + 25 * q + l];\
            }                                                                 \
            float accA0 = 0.f, accA1 = 0.f, accB0 = 0.f, accB1 = 0.f;         \
            CMALL                                                             \
            if (l < 50) {                                                     \
                part[PPc][q][lc]      = accA0 + accA1;                        \
                part[PPc][q][lc + 50] = accB0 + accB1;                        \
            }                                                                 \
            BARRIER                                                           \
            if (l < 25) {                                                     \
                const int r = 25 * q + l;                                     \
                float x = ((part[PPc][0][r] + part[PPc][1][r]) +              \
                           (part[PPc][2][r] + part[PPc][3][r])) +             \
                          ((cp0 + cp1) + (cp2 + cp3));                        \
                if (ri >= Lc) {                                               \
                    const int n = ri - Lc;                                    \
                    if (n < tc) x += slow_dot(&hist[n * Ec],                  \
                                              W1 + (size_t)r * W1cols + Ec);  \
                }                                                             \
                const float u = __expf(2.f * x);                              \
                vh = 1.f - 2.f / (u + 1.f);    /* tanh, exact identity */     \
                hist[tc * Ec + r] = vh;        /* generic paths only */       \
            }                                                                 \
            __builtin_amdgcn_s_setprio(0);                                    \
            if (tc + 1 < Tc) cc = ccS[tc + 1];                                \
        } else {                                                              \
            BARRIER                                                           \
        }                                                                     \
    } else {                                                                  \
        /* [1] stage row loaded last tick (for t=i+4) into slot i&3 */        \
        if (l < 25) embS[i_ & 3][q][l] = eR;                                  \
        /* [2] issue load for t=i+5 (3-tick flight) */                        \
        {                                                                     \
            const int t5 = i_ + 5;                                            \
            const int tk5 = (t5 < Tc) ? RF(tokRS[t5]) : -1;                   \
            eR = 0.f;                                                         \
            if (tk5 >= 0 && l < 25) eR = emb[(size_t)tk5 * Ec + 25 * q + l];  \
        }                                                                     \
        /* [3] compute cpart[t=i+2] from slot (i+2)&3 via pk_fma */           \
        {                                                                     \
            const int t = i_ + 2;                                             \
            if (t < Tc) { PCOMP(t) }                                          \
        }                                                                     \
        BARRIER                                                               \
    }                                                                         \
}

    // ---- main loop: 256 ticks, unroll-2 ----
    #pragma unroll 1
    for (int i2 = 0; i2 < 256; i2 += 2) {
        TICK(i2,     1)
        TICK(i2 + 1, 0)
    }
#undef TICK
#undef BARRIER

    // ---- out[b] = sigmoid(W2 . h_254 + b2) ----
    if (cons) {
        float pv = 0.f;
        if (l < 25) pv = W2[25 * q + l] * vh;
        #pragma unroll
        for (int off = 32; off > 0; off >>= 1) pv += __shfl_down(pv, off, 64);
        if (l == 0) red[q] = pv;
    }
    __syncthreads();
    if (tid == 0)
        out[b] = 1.f / (1.f + __expf(-((red[0] + red[1]) + (red[2] + red[3]) + b2[0])));
}

extern "C" void kernel_launch(void* const* d_in, const int* in_sizes, int n_in,
                              void* d_out, int out_size, void* d_ws, size_t ws_size,
                              hipStream_t stream) {
    const int*   token_ids  = (const int*)  d_in[0];
    const int*   comp_left  = (const int*)  d_in[1];
    const int*   comp_right = (const int*)  d_in[2];
    const float* emb        = (const float*)d_in[3];
    const float* W1         = (const float*)d_in[4];
    const float* b1         = (const float*)d_in[5];
    const float* W2         = (const float*)d_in[6];
    const float* b2         = (const float*)d_in[7];
    float*       out        = (float*)d_out;

    fused<<<Bc, 512, 0, stream>>>(token_ids, comp_left, comp_right,
                                  emb, W1, b1, W2, b2, out);
}

// Round 21
// 135.794 us; speedup vs baseline: 1.4429x; 1.4429x over previous
//
#include <hip/hip_runtime.h>
#include <math.h>

// RecurNN: B=256, L=256, E=100, T=255.
// x_t = W1L*left_t + W1R*right_t + b1; h_t = tanh(x_t); out = sigmoid(W2 h_254 + b2).
// These inputs: right_t always a leaf; left_t = node t-1 (leaf only at t=0).
//
// R21 = R20 (pk_fma producer) with the prefetch flight FIXED at 2 ticks:
//  - eR0/eR1 ping-pong: load issued at tick i is staged (ds_write) at tick
//    i+2 (~2400 cyc slack) -- R20 had 1-tick slack, exposing global latency
//    in every tick's vmcnt wait (131us -> 196us regression, VALUBusy 55->33).
//  - embS zero-init (element 25 of each row was uninitialized garbage
//    entering a x0 pk_fma -- NaN hazard).
//  - pk_fma asm non-volatile (data deps order it; scheduler can interleave).
// Consumer unchanged from R19 (RL from own vh, setprio, hoisted cpart read,
// stride-1 partials). One "lgkmcnt(0); s_barrier" per tick; vmcnt not drained.

#define Bc 256
#define Lc 256
#define Ec 100
#define Tc 255
#define W1cols 200

#define RL(v, k) __int_as_float(__builtin_amdgcn_readlane(__float_as_int(v), (k)))
#define RF(x)    __builtin_amdgcn_readfirstlane(x)

// ---- consumer: 25 weight pairs (50 named scalars) ----
#define REP25(X) X(0) X(1) X(2) X(3) X(4) X(5) X(6) X(7) X(8) X(9) X(10) X(11) X(12) \
                 X(13) X(14) X(15) X(16) X(17) X(18) X(19) X(20) X(21) X(22) X(23) X(24)
#define DECLWC(j) float wA##j, wB##j;
#define LOADWC(j) { wA##j = crowA[j]; wB##j = crowB[j]; }
#define CM2(a,b) { const float ra_ = RL(sv,(a)), rb_ = RL(sv,(b)); \
    accA0 = fmaf(ra_, wA##a, accA0); accB0 = fmaf(ra_, wB##a, accB0); \
    accA1 = fmaf(rb_, wA##b, accA1); accB1 = fmaf(rb_, wB##b, accB1); }
#define CM1(a) { const float ra_ = RL(sv,(a)); \
    accA0 = fmaf(ra_, wA##a, accA0); accB0 = fmaf(ra_, wB##a, accB0); }
#define CMALL CM2(0,1) CM2(2,3) CM2(4,5) CM2(6,7) CM2(8,9) CM2(10,11) CM2(12,13) \
              CM2(14,15) CM2(16,17) CM2(18,19) CM2(20,21) CM2(22,23) CM1(24)

// ---- producer: 13 float2 weight k-pairs per row, pk_fma ----
#define REP13(X) X(0) X(1) X(2) X(3) X(4) X(5) X(6) X(7) X(8) X(9) X(10) X(11) X(12)
#define DECLWP(j) float2 pA##j, pB##j;
#define LOADWP(j) { pA##j = make_float2(prowA[2*(j)], (2*(j)+1 < 25) ? prowA[2*(j)+1] : 0.f); \
                    pB##j = make_float2(prowB[2*(j)], (2*(j)+1 < 25) ? prowB[2*(j)+1] : 0.f); }
// packed fma: A.{x,y} += W.{x,y} * H.{x,y}  (64-bit VGPR pairs; non-volatile)
#define PPK(A, W, H) asm("v_pk_fma_f32 %0, %1, %2, %0" : "+v"(A) : "v"(W), "v"(H));
#define PSTEP(j) { const float2 h_ = *(const float2*)(eb + 2*(j)); \
                   PPK(aA, pA##j, h_) PPK(aB, pB##j, h_) }
#define PCOMP(T) { \
    const float* eb = &embS[(T) & 3][q][0]; \
    float2 aA = make_float2(b1eA, 0.f), aB = make_float2(b1eB, 0.f); \
    REP13(PSTEP) \
    if (l < 50) { \
        cpart[(T) & 7][q][lc]      = aA.x + aA.y; \
        cpart[(T) & 7][q][lc + 50] = aB.x + aB.y; \
    } }

// generic fallback dot (global weights; never hot for these inputs)
__device__ __noinline__ float slow_dot(const float* rp, const float* wr) {
    float a0 = 0.f, a1 = 0.f, a2 = 0.f, a3 = 0.f;
    for (int qq = 0; qq < 25; ++qq) {
        float4 h4 = *(const float4*)(rp + 4 * qq);
        float4 w4 = *(const float4*)(wr + 4 * qq);
        a0 = fmaf(w4.x, h4.x, a0); a1 = fmaf(w4.y, h4.y, a1);
        a2 = fmaf(w4.z, h4.z, a2); a3 = fmaf(w4.w, h4.w, a3);
    }
    return (a0 + a1) + (a2 + a3);
}

__global__ __launch_bounds__(512, 2)
void fused(const int* __restrict__ token_ids,
           const int* __restrict__ comp_left,
           const int* __restrict__ comp_right,
           const float* __restrict__ emb,
           const float* __restrict__ W1,
           const float* __restrict__ b1,
           const float* __restrict__ W2,
           const float* __restrict__ b2,
           float* __restrict__ out)
{
    const int b    = blockIdx.x;
    const int tid  = threadIdx.x;          // 0..511
    const int wv   = tid >> 6;             // 0..3 consumers; 4..7 producers
    const int l    = tid & 63;
    const bool cons = (wv < 4);
    const int q    = wv & 3;               // consumer k-slice / producer k-quarter
    const int lc   = (l < 50) ? l : 49;

    __shared__ float hist[Tc * Ec];                  // generic paths only
    __shared__ float part[2][4][Ec];                 // cons partials, stride-1
    __shared__ float cpart[8][4][Ec];                // c partials, stride-1
    __shared__ __align__(16) float embS[4][4][28];   // emb quarter ring (zeroed)
    __shared__ int2  ccS[Tc];
    __shared__ int   tokRS[Tc], tokLS[Tc];
    __shared__ float red[4];

    // ---- staging ----
    for (int i = tid; i < Tc; i += 512) {
        const int cl = comp_left [b * Tc + i];
        const int cr = comp_right[b * Tc + i];
        ccS[i]   = make_int2(cl, cr);
        tokRS[i] = (cr < Lc) ? token_ids[b * Lc + cr] : -1;
        tokLS[i] = (cl < Lc) ? token_ids[b * Lc + cl] : -1;
    }
    if (tid < 448) ((float*)embS)[tid] = 0.f;        // NaN-hazard kill

    // ---- weights ----
    const float* crowA = W1 + (size_t)lc * W1cols + 25 * q;
    const float* crowB = W1 + (size_t)(lc + 50) * W1cols + 25 * q;
    REP25(DECLWC)
    const float* prowA = W1 + (size_t)lc * W1cols + Ec + 25 * q;
    const float* prowB = W1 + (size_t)(lc + 50) * W1cols + Ec + 25 * q;
    REP13(DECLWP)
    if (cons) { REP25(LOADWC) }
    else      { REP13(LOADWP) }
    const float b1eA = (!cons && q == 0) ? b1[lc] : 0.f;
    const float b1eB = (!cons && q == 0) ? b1[lc + 50] : 0.f;

    __syncthreads();   // staging (incl. embS zero) + weights visible

    // ---- state ----
    float vh = 0.f;                        // consumer lane j<25: h[25q+j]
    int2  cc = make_int2(0, 0);
    float eR0 = 0.f, eR1 = 0.f;            // producer in-flight rows (ping-pong)

    if (cons) {
        cc = ccS[0];
    } else {
        // ---- producer prologue: stage slots t=0..3; cpart[0],[1]; load t=4,5 ----
        #pragma unroll
        for (int t = 0; t < 4; ++t) {
            const int tk = RF(tokRS[t]);
            float v = 0.f;
            if (tk >= 0 && l < 25) v = emb[(size_t)tk * Ec + 25 * q + l];
            if (l < 25) embS[t][q][l] = v;
        }
        PCOMP(0)      // own-wave write->read: DS pipe in-order
        PCOMP(1)
        const int tk4 = RF(tokRS[4]);
        if (tk4 >= 0 && l < 25) eR0 = emb[(size_t)tk4 * Ec + 25 * q + l];
        const int tk5 = RF(tokRS[5]);
        if (tk5 >= 0 && l < 25) eR1 = emb[(size_t)tk5 * Ec + 25 * q + l];
    }

#define BARRIER asm volatile("s_waitcnt lgkmcnt(0)\n\ts_barrier" ::: "memory");

// one tick: I runtime index, PPc compile-time cons ping-pong, PAR = I&1
#define TICK(I, PPc, PAR)                                                     \
{                                                                             \
    const int i_ = (I);                                                       \
    if (cons) {                                                               \
        const int tc = i_ - 1;                                                \
        if (tc >= 0) {                                                        \
            __builtin_amdgcn_s_setprio(1);                                    \
            const int li = RF(cc.x);                                          \
            const int ri = RF(cc.y);                                          \
            /* cpart[tc] written >=2 barriers ago: read early, latency hides  \
               under CMALL issue. */                                          \
            float cp0 = 0.f, cp1 = 0.f, cp2 = 0.f, cp3 = 0.f;                 \
            if (l < 25) {                                                     \
                const int r_ = 25 * q + l;                                    \
                cp0 = cpart[tc & 7][0][r_]; cp1 = cpart[tc & 7][1][r_];       \
                cp2 = cpart[tc & 7][2][r_]; cp3 = cpart[tc & 7][3][r_];       \
            }                                                                 \
            float sv = 0.f;                                                   \
            if (tc >= 1 && li == Lc + tc - 1) {                               \
                sv = vh;                       /* register fast path */       \
            } else if (li >= Lc) {                                            \
                const int n = li - Lc;                                        \
                if (n < tc && l < 25) sv = hist[n * Ec + 25 * q + l];         \
            } else {                                                          \
                const int tl = RF(tokLS[tc]);                                 \
                if (tl >= 0 && l < 25) sv = emb[(size_t)tl * Ec + 25 * q + l];\
            }                                                                 \
            float accA0 = 0.f, accA1 = 0.f, accB0 = 0.f, accB1 = 0.f;         \
            CMALL                                                             \
            if (l < 50) {                                                     \
                part[PPc][q][lc]      = accA0 + accA1;                        \
                part[PPc][q][lc + 50] = accB0 + accB1;                        \
            }                                                                 \
            BARRIER                                                           \
            if (l < 25) {                                                     \
                const int r = 25 * q + l;                                     \
                float x = ((part[PPc][0][r] + part[PPc][1][r]) +              \
                           (part[PPc][2][r] + part[PPc][3][r])) +             \
                          ((cp0 + cp1) + (cp2 + cp3));                        \
                if (ri >= Lc) {                                               \
                    const int n = ri - Lc;                                    \
                    if (n < tc) x += slow_dot(&hist[n * Ec],                  \
                                              W1 + (size_t)r * W1cols + Ec);  \
                }                                                             \
                const float u = __expf(2.f * x);                              \
                vh = 1.f - 2.f / (u + 1.f);    /* tanh, exact identity */     \
                hist[tc * Ec + r] = vh;        /* generic paths only */       \
            }                                                                 \
            __builtin_amdgcn_s_setprio(0);                                    \
            if (tc + 1 < Tc) cc = ccS[tc + 1];                                \
        } else {                                                              \
            BARRIER                                                           \
        }                                                                     \
    } else {                                                                  \
        /* [1] stage row for t=i+4 (loaded 2 ticks ago) into slot i&3 */      \
        if (l < 25) embS[i_ & 3][q][l] = (PAR) ? eR1 : eR0;                   \
        /* [2] issue load for t=i+6 (2-tick flight) into freed register */    \
        {                                                                     \
            const int t6 = i_ + 6;                                            \
            const int tk6 = (t6 < Tc) ? RF(tokRS[t6]) : -1;                   \
            float nv = 0.f;                                                   \
            if (tk6 >= 0 && l < 25) nv = emb[(size_t)tk6 * Ec + 25 * q + l];  \
            if (PAR) eR1 = nv; else eR0 = nv;                                 \
        }                                                                     \
        /* [3] compute cpart[t=i+2] from slot (i+2)&3 via pk_fma */           \
        {                                                                     \
            const int t = i_ + 2;                                             \
            if (t < Tc) { PCOMP(t) }                                          \
        }                                                                     \
        BARRIER                                                               \
    }                                                                         \
}

    // ---- main loop: 256 ticks, unroll-2 ----
    #pragma unroll 1
    for (int i2 = 0; i2 < 256; i2 += 2) {
        TICK(i2,     1, 0)
        TICK(i2 + 1, 0, 1)
    }
#undef TICK
#undef BARRIER

    // ---- out[b] = sigmoid(W2 . h_254 + b2) ----
    if (cons) {
        float pv = 0.f;
        if (l < 25) pv = W2[25 * q + l] * vh;
        #pragma unroll
        for (int off = 32; off > 0; off >>= 1) pv += __shfl_down(pv, off, 64);
        if (l == 0) red[q] = pv;
    }
    __syncthreads();
    if (tid == 0)
        out[b] = 1.f / (1.f + __expf(-((red[0] + red[1]) + (red[2] + red[3]) + b2[0])));
}

extern "C" void kernel_launch(void* const* d_in, const int* in_sizes, int n_in,
                              void* d_out, int out_size, void* d_ws, size_t ws_size,
                              hipStream_t stream) {
    const int*   token_ids  = (const int*)  d_in[0];
    const int*   comp_left  = (const int*)  d_in[1];
    const int*   comp_right = (const int*)  d_in[2];
    const float* emb        = (const float*)d_in[3];
    const float* W1         = (const float*)d_in[4];
    const float* b1         = (const float*)d_in[5];
    const float* W2         = (const float*)d_in[6];
    const float* b2         = (const float*)d_in[7];
    float*       out        = (float*)d_out;

    fused<<<Bc, 512, 0, stream>>>(token_ids, comp_left, comp_right,
                                  emb, W1, b1, W2, b2, out);
}